// Round 1
// baseline (24.635 us; speedup 1.0000x reference)
//
#include <hip/hip_runtime.h>
#include <stdint.h>

// StringLabelEncoder: for each input row (4x int32 = 128-bit key), find the
// index of the (unique) matching row in the class table [M=50000, 4].
// Strategy: build an open-addressing hash table in d_ws (insert kernel),
// then probe it (lookup kernel). Keys are distinct (random 128-bit), so
// insertion only needs atomicCAS on the value slot, no key compare.

#define HASH_EMPTY (-1)

__device__ __forceinline__ uint32_t hash4(int4 k) {
    uint32_t ws[4] = {(uint32_t)k.x, (uint32_t)k.y, (uint32_t)k.z, (uint32_t)k.w};
    uint32_t h = 0x9e3779b9u;
#pragma unroll
    for (int i = 0; i < 4; ++i) {
        uint32_t x = ws[i] * 0xcc9e2d51u;
        x = (x << 15) | (x >> 17);
        x *= 0x1b873593u;
        h ^= x;
        h = (h << 13) | (h >> 19);
        h = h * 5u + 0xe6546b64u;
    }
    h ^= h >> 16; h *= 0x85ebca6bu;
    h ^= h >> 13; h *= 0xc2b2ae35u;
    h ^= h >> 16;
    return h;
}

__global__ void sle_fill_kernel(int* __restrict__ vals, int ts) {
    int i = blockIdx.x * blockDim.x + threadIdx.x;
    if (i < ts) vals[i] = HASH_EMPTY;
}

__global__ void sle_insert_kernel(const int4* __restrict__ cls, int M,
                                  int* __restrict__ vals, int4* __restrict__ keys,
                                  uint32_t mask) {
    int i = blockIdx.x * blockDim.x + threadIdx.x;
    if (i >= M) return;
    int4 k = cls[i];
    uint32_t s = hash4(k) & mask;
    while (true) {
        int prev = atomicCAS(&vals[s], HASH_EMPTY, i);
        if (prev == HASH_EMPTY) {
            keys[s] = k;   // slot claimed; key visible to lookup kernel after dispatch boundary
            return;
        }
        s = (s + 1) & mask;
    }
}

__global__ void sle_lookup_kernel(const int4* __restrict__ x, int N,
                                  const int* __restrict__ vals,
                                  const int4* __restrict__ keys,
                                  uint32_t mask, int* __restrict__ out) {
    int i = blockIdx.x * blockDim.x + threadIdx.x;
    if (i >= N) return;
    int4 q = x[i];
    uint32_t s = hash4(q) & mask;
    int res = 0;  // reference argmax over all-false row would give 0; should not happen
    while (true) {
        int v = vals[s];
        if (v == HASH_EMPTY) break;   // absent (cannot happen per problem statement)
        int4 k = keys[s];
        if (k.x == q.x && k.y == q.y && k.z == q.z && k.w == q.w) { res = v; break; }
        s = (s + 1) & mask;
    }
    out[i] = res;
}

// Fallback if the workspace is too small for the hash table: block-per-row scan.
__global__ void sle_brute_kernel(const int4* __restrict__ x, int N,
                                 const int4* __restrict__ cls, int M,
                                 int* __restrict__ out) {
    __shared__ int found;
    int row = blockIdx.x;
    if (row >= N) return;
    if (threadIdx.x == 0) found = 0;
    __syncthreads();
    int4 q = x[row];
    for (int c = threadIdx.x; c < M; c += blockDim.x) {
        int4 k = cls[c];
        if (k.x == q.x && k.y == q.y && k.z == q.z && k.w == q.w) found = c;  // single writer
    }
    __syncthreads();
    if (threadIdx.x == 0) out[row] = found;
}

extern "C" void kernel_launch(void* const* d_in, const int* in_sizes, int n_in,
                              void* d_out, int out_size, void* d_ws, size_t ws_size,
                              hipStream_t stream) {
    const int4* x   = (const int4*)d_in[0];           // [N, 4] int32
    const int4* cls = (const int4*)d_in[1];           // [M, 4] int32
    const int N = in_sizes[0] / 4;
    const int M = in_sizes[1] / 4;
    int* out = (int*)d_out;                           // int32 indices (jax demotes int64->int32)

    const size_t need17 = (size_t)(1u << 17) * 20u;   // keys 16B + vals 4B per slot
    const size_t need16 = (size_t)(1u << 16) * 20u;

    uint32_t ts = 0;
    if (ws_size >= need17)      ts = 1u << 17;        // load factor ~0.38
    else if (ws_size >= need16) ts = 1u << 16;        // load factor ~0.76

    if (ts != 0 && (1u << 16) > (uint32_t)M) {
        int4* keys = (int4*)d_ws;                     // [ts] int4, 16B aligned at base
        int*  vals = (int*)((char*)d_ws + (size_t)ts * 16u);

        sle_fill_kernel<<<(ts + 255) / 256, 256, 0, stream>>>(vals, (int)ts);
        sle_insert_kernel<<<(M + 255) / 256, 256, 0, stream>>>(cls, M, vals, keys, ts - 1);
        sle_lookup_kernel<<<(N + 255) / 256, 256, 0, stream>>>(x, N, vals, keys, ts - 1, out);
    } else {
        sle_brute_kernel<<<N, 256, 0, stream>>>(x, N, cls, M, out);
    }
}

// Round 2
// 21.107 us; speedup vs baseline: 1.1671x; 1.1671x over previous
//
#include <hip/hip_runtime.h>
#include <stdint.h>

// StringLabelEncoder: for each input row (4x int32 = 128-bit key), find the
// index of the (unique) matching row in the class table [M=50000, 4].
//
// Single-dispatch design: the QUERY side (N=4096 rows) is small, so each
// block builds its own open-addressing hash table of the query rows in LDS
// (32 KB, alpha=0.5), then scans a 256-class slice of the class table,
// probing the LDS table and writing out[row] = class_idx on exact key match.
// No inter-block communication, no fill kernel, no global hash table.
// Output is insertion-order invariant: probes continue to the first EMPTY
// slot, so every entry of a cluster (incl. duplicate query keys) is found.

#define TS 8192
#define TS_MASK (TS - 1)
#define HASH_EMPTY (-1)

__device__ __forceinline__ uint32_t hash4(int4 k) {
    uint32_t ws[4] = {(uint32_t)k.x, (uint32_t)k.y, (uint32_t)k.z, (uint32_t)k.w};
    uint32_t h = 0x9e3779b9u;
#pragma unroll
    for (int i = 0; i < 4; ++i) {
        uint32_t x = ws[i] * 0xcc9e2d51u;
        x = (x << 15) | (x >> 17);
        x *= 0x1b873593u;
        h ^= x;
        h = (h << 13) | (h >> 19);
        h = h * 5u + 0xe6546b64u;
    }
    h ^= h >> 16; h *= 0x85ebca6bu;
    h ^= h >> 13; h *= 0xc2b2ae35u;
    h ^= h >> 16;
    return h;
}

__global__ __launch_bounds__(256)
void sle_onepass_kernel(const int4* __restrict__ x, int N,
                        const int4* __restrict__ cls, int M,
                        int* __restrict__ out) {
    __shared__ int tbl[TS];

    const int tid = threadIdx.x;

    // Phase A: clear the LDS table.
#pragma unroll
    for (int s = tid; s < TS; s += 256) tbl[s] = HASH_EMPTY;
    __syncthreads();

    // Phase B: insert all N query rows (row index as value; no key stored —
    // exact compare later reads x[v] from L2). Duplicate keys occupy
    // separate slots; that's fine (all matching entries get written).
    for (int r = tid; r < N; r += 256) {
        int4 k = x[r];
        uint32_t s = hash4(k) & TS_MASK;
        while (atomicCAS(&tbl[s], HASH_EMPTY, r) != HASH_EMPTY) {
            s = (s + 1) & TS_MASK;
        }
    }
    __syncthreads();

    // Phase C: scan this block's slice of the class table.
    const int c = blockIdx.x * 256 + tid;
    if (c < M) {
        int4 q = cls[c];
        uint32_t s = hash4(q) & TS_MASK;
        int v;
        while ((v = tbl[s]) != HASH_EMPTY) {
            int4 k = x[v];
            if (k.x == q.x && k.y == q.y && k.z == q.z && k.w == q.w) {
                out[v] = c;   // each row matches exactly one class: no race
            }
            s = (s + 1) & TS_MASK;
        }
    }
}

// Fallback for shapes where the LDS table would overflow: block-per-row scan.
__global__ void sle_brute_kernel(const int4* __restrict__ x, int N,
                                 const int4* __restrict__ cls, int M,
                                 int* __restrict__ out) {
    __shared__ int found;
    int row = blockIdx.x;
    if (row >= N) return;
    if (threadIdx.x == 0) found = 0;
    __syncthreads();
    int4 q = x[row];
    for (int c = threadIdx.x; c < M; c += blockDim.x) {
        int4 k = cls[c];
        if (k.x == q.x && k.y == q.y && k.z == q.z && k.w == q.w) found = c;
    }
    __syncthreads();
    if (threadIdx.x == 0) out[row] = found;
}

extern "C" void kernel_launch(void* const* d_in, const int* in_sizes, int n_in,
                              void* d_out, int out_size, void* d_ws, size_t ws_size,
                              hipStream_t stream) {
    const int4* x   = (const int4*)d_in[0];   // [N, 4] int32
    const int4* cls = (const int4*)d_in[1];   // [M, 4] int32
    const int N = in_sizes[0] / 4;
    const int M = in_sizes[1] / 4;
    int* out = (int*)d_out;                   // int32 (jax demotes int64 -> int32)

    if (N <= TS * 3 / 4) {
        int blocks = (M + 255) / 256;
        sle_onepass_kernel<<<blocks, 256, 0, stream>>>(x, N, cls, M, out);
    } else {
        sle_brute_kernel<<<N, 256, 0, stream>>>(x, N, cls, M, out);
    }
}

// Round 3
// 17.587 us; speedup vs baseline: 1.4007x; 1.2002x over previous
//
#include <hip/hip_runtime.h>
#include <stdint.h>

// StringLabelEncoder: for each input row (4x int32 = 128-bit key), find the
// index of the (unique) matching row in the class table [M=50000, 4].
//
// Single-dispatch design: each block builds an open-addressing hash table of
// the N=4096 query rows in LDS, then scans a 256-class slice of the class
// table, probing the LDS table and writing out[row] = class_idx on match.
//
// This revision, vs round 2:
//  - all independent global loads (16 x-keys + 1 cls row per thread) are
//    issued BEFORE the LDS clear, so HBM/L2 latency hides under it
//  - hash is just (k.x & MASK): input words are uniformly random, so the
//    murmur-style mix was pure VALU overhead (probing + full compare make
//    32-bit hash collisions a perf non-event, not a correctness one)
//  - a parallel LDS verify array holds (k.x, k.y) per slot, so probe
//    iterations never touch global memory; only a true (x,y) match reads
//    x[v] once to confirm (z,w). Expected false (x,y) matches ~2^-32.
// Output is insertion-order invariant (probe chains scanned to EMPTY), so
// the kernel's OUTPUT is deterministic even though CAS race order is not.

#define TS 8192
#define TS_MASK (TS - 1)
#define HASH_EMPTY (-1)
#define KPT 16   // keys per thread: supports N <= 256*KPT = 4096

__global__ __launch_bounds__(256)
void sle_onepass_kernel(const int4* __restrict__ x, int N,
                        const int4* __restrict__ cls, int M,
                        int* __restrict__ out) {
    __shared__ int  vals[TS];   // row index or EMPTY
    __shared__ int2 vkey[TS];   // (k.x, k.y) verify words

    const int tid = threadIdx.x;
    const int c   = blockIdx.x * 256 + tid;

    // ---- Issue all independent global loads up front (latency overlap). ----
    int4 q = make_int4(0, 0, 0, 0);
    if (c < M) q = cls[c];

    int4 k[KPT];
#pragma unroll
    for (int i = 0; i < KPT; ++i) {
        const int r = tid + i * 256;
        if (r < N) k[i] = x[r];
    }

    // ---- Clear the value table while loads are in flight. ----
#pragma unroll
    for (int i = 0; i < TS / 256; ++i) vals[tid + i * 256] = HASH_EMPTY;
    __syncthreads();

    // ---- Insert all query rows (value = row index). ----
#pragma unroll
    for (int i = 0; i < KPT; ++i) {
        const int r = tid + i * 256;
        if (r < N) {
            uint32_t s = (uint32_t)k[i].x & TS_MASK;
            while (atomicCAS(&vals[s], HASH_EMPTY, r) != HASH_EMPTY)
                s = (s + 1) & TS_MASK;
            vkey[s] = make_int2(k[i].x, k[i].y);   // visible after barrier
        }
    }
    __syncthreads();

    // ---- Probe for this block's class. ----
    if (c < M) {
        uint32_t s = (uint32_t)q.x & TS_MASK;
        int v;
        while ((v = vals[s]) != HASH_EMPTY) {
            const int2 kv = vkey[s];
            if (kv.x == q.x && kv.y == q.y) {
                const int4 kk = x[v];               // rare: true matches only
                if (kk.z == q.z && kk.w == q.w) out[v] = c;
            }
            s = (s + 1) & TS_MASK;
        }
    }
}

// Fallback for shapes where the per-thread key cache / LDS table would
// overflow: block-per-row scan of the class table.
__global__ void sle_brute_kernel(const int4* __restrict__ x, int N,
                                 const int4* __restrict__ cls, int M,
                                 int* __restrict__ out) {
    __shared__ int found;
    int row = blockIdx.x;
    if (row >= N) return;
    if (threadIdx.x == 0) found = 0;
    __syncthreads();
    int4 q = x[row];
    for (int c = threadIdx.x; c < M; c += blockDim.x) {
        int4 k = cls[c];
        if (k.x == q.x && k.y == q.y && k.z == q.z && k.w == q.w) found = c;
    }
    __syncthreads();
    if (threadIdx.x == 0) out[row] = found;
}

extern "C" void kernel_launch(void* const* d_in, const int* in_sizes, int n_in,
                              void* d_out, int out_size, void* d_ws, size_t ws_size,
                              hipStream_t stream) {
    const int4* x   = (const int4*)d_in[0];   // [N, 4] int32
    const int4* cls = (const int4*)d_in[1];   // [M, 4] int32
    const int N = in_sizes[0] / 4;
    const int M = in_sizes[1] / 4;
    int* out = (int*)d_out;                   // int32 (jax demotes int64 -> int32)

    if (N <= 256 * KPT && N <= TS * 3 / 4) {
        int blocks = (M + 255) / 256;
        sle_onepass_kernel<<<blocks, 256, 0, stream>>>(x, N, cls, M, out);
    } else {
        sle_brute_kernel<<<N, 256, 0, stream>>>(x, N, cls, M, out);
    }
}